// Round 1
// baseline (7496.008 us; speedup 1.0000x reference)
//
#include <hip/hip_runtime.h>
#include <math.h>

#define RAYS 2048
// N_COARSE=128, N_IMP=64, N_ALL=192, W=256

// ---------------- helpers ----------------
__device__ __forceinline__ float sp_act(float x) {           // jax.nn.softplus
    return fmaxf(x, 0.0f) + log1pf(expf(-fabsf(x)));
}
__device__ __forceinline__ float lap_cdf(float x, float beta) {
    return (x <= 0.0f) ? 0.5f * expf(x / beta) : 1.0f - 0.5f * expf(-x / beta);
}
__device__ __forceinline__ float sigm(float x) { return 1.0f / (1.0f + expf(-x)); }

// Tile GEMM: OUT[p][j] = act( sum_k IN[p][k]*Wm[k*256+j] + bias[j] )
// 256 threads, P=16 points, LDS IN/OUT [16][256]. MODE: 0=linear 1=softplus 2=relu
template<int MODE, bool BIAS>
__device__ __forceinline__ void tile_mm(const float* __restrict__ Wm,
                                        const float* __restrict__ bias,
                                        const float* IN, float* OUT)
{
    const int t  = threadIdx.x;
    const int j0 = (t & 63) << 2;
    const int p0 = (t >> 6) << 2;
    float acc[4][4];
#pragma unroll
    for (int a = 0; a < 4; ++a)
#pragma unroll
        for (int b = 0; b < 4; ++b) acc[a][b] = 0.0f;

    for (int k = 0; k < 256; k += 4) {
        const float4 w0 = *(const float4*)(Wm + (k + 0) * 256 + j0);
        const float4 w1 = *(const float4*)(Wm + (k + 1) * 256 + j0);
        const float4 w2 = *(const float4*)(Wm + (k + 2) * 256 + j0);
        const float4 w3 = *(const float4*)(Wm + (k + 3) * 256 + j0);
#pragma unroll
        for (int pp = 0; pp < 4; ++pp) {
            const float4 av = *(const float4*)(IN + (p0 + pp) * 256 + k);
            acc[pp][0] = fmaf(av.x, w0.x, acc[pp][0]);
            acc[pp][1] = fmaf(av.x, w0.y, acc[pp][1]);
            acc[pp][2] = fmaf(av.x, w0.z, acc[pp][2]);
            acc[pp][3] = fmaf(av.x, w0.w, acc[pp][3]);
            acc[pp][0] = fmaf(av.y, w1.x, acc[pp][0]);
            acc[pp][1] = fmaf(av.y, w1.y, acc[pp][1]);
            acc[pp][2] = fmaf(av.y, w1.z, acc[pp][2]);
            acc[pp][3] = fmaf(av.y, w1.w, acc[pp][3]);
            acc[pp][0] = fmaf(av.z, w2.x, acc[pp][0]);
            acc[pp][1] = fmaf(av.z, w2.y, acc[pp][1]);
            acc[pp][2] = fmaf(av.z, w2.z, acc[pp][2]);
            acc[pp][3] = fmaf(av.z, w2.w, acc[pp][3]);
            acc[pp][0] = fmaf(av.w, w3.x, acc[pp][0]);
            acc[pp][1] = fmaf(av.w, w3.y, acc[pp][1]);
            acc[pp][2] = fmaf(av.w, w3.z, acc[pp][2]);
            acc[pp][3] = fmaf(av.w, w3.w, acc[pp][3]);
        }
    }
    float bv0 = 0.f, bv1 = 0.f, bv2 = 0.f, bv3 = 0.f;
    if constexpr (BIAS) { bv0 = bias[j0]; bv1 = bias[j0+1]; bv2 = bias[j0+2]; bv3 = bias[j0+3]; }
#pragma unroll
    for (int pp = 0; pp < 4; ++pp) {
        float r0 = acc[pp][0] + bv0;
        float r1 = acc[pp][1] + bv1;
        float r2 = acc[pp][2] + bv2;
        float r3 = acc[pp][3] + bv3;
        if constexpr (MODE == 1) { r0 = sp_act(r0); r1 = sp_act(r1); r2 = sp_act(r2); r3 = sp_act(r3); }
        if constexpr (MODE == 2) { r0 = fmaxf(r0,0.f); r1 = fmaxf(r1,0.f); r2 = fmaxf(r2,0.f); r3 = fmaxf(r3,0.f); }
        *(float4*)(OUT + (p0 + pp) * 256 + j0) = make_float4(r0, r1, r2, r3);
    }
}

// Radiance layer 0: K=265 = 9 (geometry) + 256 (feat). relu + bias.
__device__ __forceinline__ void rad0_mm(const float* __restrict__ Wm,
                                        const float* __restrict__ bias,
                                        const float (*in9)[12],
                                        const float* F, float* OUT)
{
    const int t  = threadIdx.x;
    const int j0 = (t & 63) << 2;
    const int p0 = (t >> 6) << 2;
    float acc[4][4];
#pragma unroll
    for (int a = 0; a < 4; ++a)
#pragma unroll
        for (int b = 0; b < 4; ++b) acc[a][b] = 0.0f;

#pragma unroll
    for (int k = 0; k < 9; ++k) {
        const float4 w = *(const float4*)(Wm + k * 256 + j0);
#pragma unroll
        for (int pp = 0; pp < 4; ++pp) {
            const float a = in9[p0 + pp][k];
            acc[pp][0] = fmaf(a, w.x, acc[pp][0]);
            acc[pp][1] = fmaf(a, w.y, acc[pp][1]);
            acc[pp][2] = fmaf(a, w.z, acc[pp][2]);
            acc[pp][3] = fmaf(a, w.w, acc[pp][3]);
        }
    }
    for (int k = 0; k < 256; k += 4) {
        const float4 w0 = *(const float4*)(Wm + (9 + k + 0) * 256 + j0);
        const float4 w1 = *(const float4*)(Wm + (9 + k + 1) * 256 + j0);
        const float4 w2 = *(const float4*)(Wm + (9 + k + 2) * 256 + j0);
        const float4 w3 = *(const float4*)(Wm + (9 + k + 3) * 256 + j0);
#pragma unroll
        for (int pp = 0; pp < 4; ++pp) {
            const float4 av = *(const float4*)(F + (p0 + pp) * 256 + k);
            acc[pp][0] = fmaf(av.x, w0.x, acc[pp][0]);
            acc[pp][1] = fmaf(av.x, w0.y, acc[pp][1]);
            acc[pp][2] = fmaf(av.x, w0.z, acc[pp][2]);
            acc[pp][3] = fmaf(av.x, w0.w, acc[pp][3]);
            acc[pp][0] = fmaf(av.y, w1.x, acc[pp][0]);
            acc[pp][1] = fmaf(av.y, w1.y, acc[pp][1]);
            acc[pp][2] = fmaf(av.y, w1.z, acc[pp][2]);
            acc[pp][3] = fmaf(av.y, w1.w, acc[pp][3]);
            acc[pp][0] = fmaf(av.z, w2.x, acc[pp][0]);
            acc[pp][1] = fmaf(av.z, w2.y, acc[pp][1]);
            acc[pp][2] = fmaf(av.z, w2.z, acc[pp][2]);
            acc[pp][3] = fmaf(av.z, w2.w, acc[pp][3]);
            acc[pp][0] = fmaf(av.w, w3.x, acc[pp][0]);
            acc[pp][1] = fmaf(av.w, w3.y, acc[pp][1]);
            acc[pp][2] = fmaf(av.w, w3.z, acc[pp][2]);
            acc[pp][3] = fmaf(av.w, w3.w, acc[pp][3]);
        }
    }
#pragma unroll
    for (int pp = 0; pp < 4; ++pp) {
        float r0 = fmaxf(acc[pp][0] + bias[j0+0], 0.f);
        float r1 = fmaxf(acc[pp][1] + bias[j0+1], 0.f);
        float r2 = fmaxf(acc[pp][2] + bias[j0+2], 0.f);
        float r3 = fmaxf(acc[pp][3] + bias[j0+3], 0.f);
        *(float4*)(OUT + (p0 + pp) * 256 + j0) = make_float4(r0, r1, r2, r3);
    }
}

// ---------------- prep: transposes + w3 repack ----------------
__global__ __launch_bounds__(256) void prep_kernel(
    const float* __restrict__ w1, const float* __restrict__ w2, const float* __restrict__ w3,
    float* __restrict__ w1T, float* __restrict__ w2T,
    float* __restrict__ w3f, float* __restrict__ w3c0)
{
    const int idx = blockIdx.x * 256 + threadIdx.x;   // 65536
    const int r = idx >> 8, c = idx & 255;
    w1T[idx] = w1[c * 256 + r];       // w1T[r][c] = w1[c][r]
    w2T[idx] = w2[c * 256 + r];
    w3f[idx] = w3[r * 257 + 1 + c];   // aligned copy of w3[:,1:257]
    if (idx < 256) w3c0[idx] = w3[idx * 257];
}

// ---------------- coarse SDF ----------------
__global__ __launch_bounds__(256) void coarse_kernel(
    const float* __restrict__ rays_o, const float* __restrict__ rays_d,
    const float* __restrict__ w0, const float* __restrict__ b0,
    const float* __restrict__ w1, const float* __restrict__ b1,
    const float* __restrict__ w2, const float* __restrict__ b2,
    const float* __restrict__ w3c0, const float* __restrict__ b3,
    float* __restrict__ sdf_out)
{
    __shared__ float A[16 * 256];
    __shared__ float B[16 * 256];
    __shared__ float pts[16][3];
    const int t = threadIdx.x;
    const int base = blockIdx.x * 16;

    if (t < 16) {
        int pg = base + t;
        int ray = pg >> 7, i = pg & 127;
        float ox = rays_o[ray*3+0], oy = rays_o[ray*3+1], oz = rays_o[ray*3+2];
        float dx = rays_d[ray*3+0], dy = rays_d[ray*3+1], dz = rays_d[ray*3+2];
        float n = sqrtf(dx*dx + dy*dy + dz*dz);
        dx /= n; dy /= n; dz /= n;
        float dv = 6.0f * ((float)i / 127.0f);
        pts[t][0] = ox + dx * dv; pts[t][1] = oy + dy * dv; pts[t][2] = oz + dz * dv;
    }
    __syncthreads();
    {   // L0 -> A
        float wa = w0[t], wb = w0[256 + t], wc = w0[512 + t], bb = b0[t];
#pragma unroll
        for (int p = 0; p < 16; ++p) {
            float z = fmaf(pts[p][0], wa, fmaf(pts[p][1], wb, fmaf(pts[p][2], wc, bb)));
            A[p * 256 + t] = sp_act(z);
        }
    }
    __syncthreads();
    tile_mm<1, true>(w1, b1, A, B); __syncthreads();
    tile_mm<1, true>(w2, b2, B, A); __syncthreads();
    if (t < 16) {
        float s = b3[0];
        for (int k = 0; k < 256; ++k) s = fmaf(A[t * 256 + k], w3c0[k], s);
        sdf_out[base + t] = s;
    }
}

// ---------------- per-ray sampling (coarse weights -> importance samples -> merge) ----------------
__global__ __launch_bounds__(256) void sample_kernel(
    const float* __restrict__ sdf_c,
    const float* __restrict__ alpha_p, const float* __restrict__ beta_p,
    float* __restrict__ d_all_g)
{
    __shared__ float sig[4][128];
    __shared__ float dc[4][128];
    __shared__ float wbuf[4][127];
    __shared__ float cdf[4][128];
    __shared__ float dfine[4][64];
    __shared__ float dall[4][192];
    const int t = threadIdx.x;
    const int wv = t >> 6, lane = t & 63;
    const int ray = blockIdx.x * 4 + wv;
    const float alpha = alpha_p[0], beta = beta_p[0];

    for (int i = lane; i < 128; i += 64) {
        float s = sdf_c[ray * 128 + i];
        sig[wv][i] = alpha * lap_cdf(-s, beta);
        dc[wv][i] = 6.0f * ((float)i / 127.0f);
    }
    __syncthreads();
    if (lane == 0) {
        float T = 1.0f, S = 0.0f;
        for (int i = 0; i < 127; ++i) {
            float delta = dc[wv][i + 1] - dc[wv][i];
            float a = 1.0f - expf(-sig[wv][i] * delta);
            float w = a * T;
            T *= (1.0f - a + 1e-10f);
            wbuf[wv][i] = w;
            S += (w + 1e-5f);
        }
        float c = 0.0f;
        cdf[wv][0] = 0.0f;
        for (int i = 0; i < 127; ++i) {
            c += (wbuf[wv][i] + 1e-5f) / S;
            cdf[wv][i + 1] = c;
        }
    }
    __syncthreads();
    {   // inverse-CDF sample: u = lane/63, searchsorted(cdf, u, side='left')
        float u = (float)lane / 63.0f;
        int lo = 0, hi = 128;
        while (lo < hi) { int m = (lo + hi) >> 1; if (cdf[wv][m] < u) lo = m + 1; else hi = m; }
        int below = lo - 1; if (below < 0) below = 0; if (below > 127) below = 127;
        int above = lo; if (above > 127) above = 127;
        float cb = cdf[wv][below], ca = cdf[wv][above];
        float bb = dc[wv][below], ba = dc[wv][above];
        float den = ca - cb; if (den < 1e-5f) den = 1.0f;
        float tt = (u - cb) / den;
        dfine[wv][lane] = bb + tt * (ba - bb);
    }
    __syncthreads();
    {   // merge (ties: coarse-first => strict/non-strict rank counts)
        float v = dfine[wv][lane];
        int lo = 0, hi = 128;                 // count of coarse <= v
        while (lo < hi) { int m = (lo + hi) >> 1; if (dc[wv][m] <= v) lo = m + 1; else hi = m; }
        dall[wv][lane + lo] = v;
    }
    for (int i = lane; i < 128; i += 64) {
        float v = dc[wv][i];
        int lo = 0, hi = 64;                  // count of fine < v
        while (lo < hi) { int m = (lo + hi) >> 1; if (dfine[wv][m] < v) lo = m + 1; else hi = m; }
        dall[wv][i + lo] = v;
    }
    __syncthreads();
    for (int i = lane; i < 192; i += 64) d_all_g[ray * 192 + i] = dall[wv][i];
}

// ---------------- fine pass: SDF fwd + analytic grad + radiance ----------------
__global__ __launch_bounds__(256) void fine_kernel(
    const float* __restrict__ rays_o, const float* __restrict__ rays_d,
    const float* __restrict__ dall_g,
    const float* __restrict__ w0, const float* __restrict__ b0,
    const float* __restrict__ w1, const float* __restrict__ b1,
    const float* __restrict__ w2, const float* __restrict__ b2,
    const float* __restrict__ w3f, const float* __restrict__ w3c0,
    const float* __restrict__ b3,
    const float* __restrict__ w1T, const float* __restrict__ w2T,
    const float* __restrict__ rw0, const float* __restrict__ rb0,
    const float* __restrict__ rw1, const float* __restrict__ rb1,
    const float* __restrict__ rw2, const float* __restrict__ rb2,
    float* __restrict__ fsdf, float* __restrict__ frgb)
{
    __shared__ float X[16 * 256];
    __shared__ float Y[16 * 256];
    __shared__ float Z[16 * 256];
    __shared__ float F[16 * 256];
    __shared__ float in9[16][12];   // 0-2 pt, 3-5 vdir, 6-8 normal
    const int t = threadIdx.x;
    const int base = blockIdx.x * 16;

    if (t < 16) {
        int pg = base + t;
        int ray = pg / 192, i = pg - ray * 192;
        float ox = rays_o[ray*3+0], oy = rays_o[ray*3+1], oz = rays_o[ray*3+2];
        float dx = rays_d[ray*3+0], dy = rays_d[ray*3+1], dz = rays_d[ray*3+2];
        float n = sqrtf(dx*dx + dy*dy + dz*dz);
        dx /= n; dy /= n; dz /= n;
        float dv = dall_g[ray * 192 + i];
        in9[t][0] = ox + dx * dv; in9[t][1] = oy + dy * dv; in9[t][2] = oz + dz * dv;
        in9[t][3] = dx; in9[t][4] = dy; in9[t][5] = dz;
    }
    __syncthreads();
    {   // SDF L0 -> X (h0)
        float wa = w0[t], wb = w0[256 + t], wc = w0[512 + t], bb = b0[t];
#pragma unroll
        for (int p = 0; p < 16; ++p) {
            float z = fmaf(in9[p][0], wa, fmaf(in9[p][1], wb, fmaf(in9[p][2], wc, bb)));
            X[p * 256 + t] = sp_act(z);
        }
    }
    __syncthreads();
    tile_mm<1, true>(w1, b1, X, Y); __syncthreads();     // h1 -> Y
    tile_mm<1, true>(w2, b2, Y, X); __syncthreads();     // h2 -> X
    tile_mm<0, true>(w3f, b3 + 1, X, F); __syncthreads();// feat -> F
    if (t < 16) {                                        // sdf scalar head
        float s = b3[0];
        for (int k = 0; k < 256; ++k) s = fmaf(X[t * 256 + k], w3c0[k], s);
        fsdf[base + t] = s;
    }
    __syncthreads();
    {   // g2' = sigmoid(z2) * w3[:,0] = (1-exp(-h2)) * w3c0, in place in X
        float wc0 = w3c0[t];
#pragma unroll
        for (int p = 0; p < 16; ++p) {
            float h = X[p * 256 + t];
            X[p * 256 + t] = (1.0f - expf(-h)) * wc0;
        }
    }
    __syncthreads();
    tile_mm<0, false>(w2T, nullptr, X, Z); __syncthreads();  // g1 = w2 @ g2' -> Z
    {   // g1' = sigmoid(z1) * g1 = (1-exp(-h1)) * g1
#pragma unroll
        for (int p = 0; p < 16; ++p) {
            float h = Y[p * 256 + t];
            Z[p * 256 + t] *= (1.0f - expf(-h));
        }
    }
    __syncthreads();
    tile_mm<0, false>(w1T, nullptr, Z, X); __syncthreads();  // g0 = w1 @ g1' -> X
    {   // g0' = sigmoid(z0) * g0 (z0 recomputed, 3 MACs)
        float wa = w0[t], wb = w0[256 + t], wc = w0[512 + t], bb = b0[t];
#pragma unroll
        for (int p = 0; p < 16; ++p) {
            float z = fmaf(in9[p][0], wa, fmaf(in9[p][1], wb, fmaf(in9[p][2], wc, bb)));
            X[p * 256 + t] *= sigm(z);
        }
    }
    __syncthreads();
    if (t < 48) {   // nabla[c] = sum_k w0[c][k] * g0'[k]
        int p = t / 3, c = t - p * 3;
        float s = 0.0f;
        for (int k = 0; k < 256; ++k) s = fmaf(w0[c * 256 + k], X[p * 256 + k], s);
        in9[p][6 + c] = s;
    }
    __syncthreads();
    if (t < 16) {   // normalize
        float nx = in9[t][6], ny = in9[t][7], nz = in9[t][8];
        float inv = 1.0f / (sqrtf(nx*nx + ny*ny + nz*nz) + 1e-7f);
        in9[t][6] = nx * inv; in9[t][7] = ny * inv; in9[t][8] = nz * inv;
    }
    __syncthreads();
    rad0_mm(rw0, rb0, in9, F, Y); __syncthreads();       // rad h1 -> Y
    tile_mm<2, true>(rw1, rb1, Y, X); __syncthreads();   // rad h2 -> X
    if (t < 48) {   // rgb head (256 -> 3), sigmoid
        int p = t / 3, c = t - p * 3;
        float s = rb2[c];
        for (int k = 0; k < 256; ++k) s = fmaf(X[p * 256 + k], rw2[k * 3 + c], s);
        frgb[(base + p) * 3 + c] = sigm(s);
    }
}

// ---------------- composite ----------------
__global__ __launch_bounds__(256) void composite_kernel(
    const float* __restrict__ dall_g, const float* __restrict__ fsdf,
    const float* __restrict__ frgb,
    const float* __restrict__ alpha_p, const float* __restrict__ beta_p,
    float* __restrict__ out)
{
    __shared__ float aa[4][192];
    __shared__ float da[4][192];
    const int t = threadIdx.x;
    const int wv = t >> 6, lane = t & 63;
    const int ray = blockIdx.x * 4 + wv;
    const float alpha = alpha_p[0], beta = beta_p[0];

    for (int i = lane; i < 192; i += 64) da[wv][i] = dall_g[ray * 192 + i];
    __syncthreads();
    for (int i = lane; i < 192; i += 64) {
        float s = fsdf[ray * 192 + i];
        float sg = alpha * lap_cdf(-s, beta);
        float delta = (i < 191) ? (da[wv][i + 1] - da[wv][i]) : 1e10f;
        aa[wv][i] = 1.0f - expf(-sg * delta);
    }
    __syncthreads();
    if (lane == 0) {
        float T = 1.0f, r0 = 0.f, r1 = 0.f, r2 = 0.f;
        for (int i = 0; i < 192; ++i) {
            float a = aa[wv][i];
            float w = a * T;
            T *= (1.0f - a + 1e-10f);
            const float* rp = frgb + (ray * 192 + i) * 3;
            r0 = fmaf(w, rp[0], r0);
            r1 = fmaf(w, rp[1], r1);
            r2 = fmaf(w, rp[2], r2);
        }
        out[ray * 3 + 0] = r0; out[ray * 3 + 1] = r1; out[ray * 3 + 2] = r2;
    }
}

// ---------------- launch ----------------
extern "C" void kernel_launch(void* const* d_in, const int* in_sizes, int n_in,
                              void* d_out, int out_size, void* d_ws, size_t ws_size,
                              hipStream_t stream) {
    const float* rays_o = (const float*)d_in[0];
    const float* rays_d = (const float*)d_in[1];
    const float* alpha  = (const float*)d_in[2];
    const float* beta   = (const float*)d_in[3];
    const float* sw0 = (const float*)d_in[4];
    const float* sb0 = (const float*)d_in[5];
    const float* sw1 = (const float*)d_in[6];
    const float* sb1 = (const float*)d_in[7];
    const float* sw2 = (const float*)d_in[8];
    const float* sb2 = (const float*)d_in[9];
    const float* sw3 = (const float*)d_in[10];
    const float* sb3 = (const float*)d_in[11];
    const float* rw0 = (const float*)d_in[12];
    const float* rb0 = (const float*)d_in[13];
    const float* rw1 = (const float*)d_in[14];
    const float* rb1 = (const float*)d_in[15];
    const float* rw2 = (const float*)d_in[16];
    const float* rb2 = (const float*)d_in[17];

    float* ws = (float*)d_ws;
    float* w1T   = ws;  ws += 65536;
    float* w2T   = ws;  ws += 65536;
    float* w3f   = ws;  ws += 65536;
    float* w3c0  = ws;  ws += 256;
    float* sdf_c = ws;  ws += RAYS * 128;        // 262144
    float* dall  = ws;  ws += RAYS * 192;        // 393216
    float* fsdf  = ws;  ws += RAYS * 192;        // 393216
    float* frgb  = ws;  ws += RAYS * 192 * 3;    // 1179648

    prep_kernel<<<256, 256, 0, stream>>>(sw1, sw2, sw3, w1T, w2T, w3f, w3c0);
    coarse_kernel<<<RAYS * 128 / 16, 256, 0, stream>>>(
        rays_o, rays_d, sw0, sb0, sw1, sb1, sw2, sb2, w3c0, sb3, sdf_c);
    sample_kernel<<<RAYS / 4, 256, 0, stream>>>(sdf_c, alpha, beta, dall);
    fine_kernel<<<RAYS * 192 / 16, 256, 0, stream>>>(
        rays_o, rays_d, dall,
        sw0, sb0, sw1, sb1, sw2, sb2, w3f, w3c0, sb3,
        w1T, w2T, rw0, rb0, rw1, rb1, rw2, rb2,
        fsdf, frgb);
    composite_kernel<<<RAYS / 4, 256, 0, stream>>>(dall, fsdf, frgb, alpha, beta, (float*)d_out);
}

// Round 4
// 6582.775 us; speedup vs baseline: 1.1387x; 1.1387x over previous
//
#include <hip/hip_runtime.h>
#include <math.h>

#define RAYS 2048
// N_COARSE=128, N_IMP=64, N_ALL=192, W=256

typedef unsigned short ushort_t;
typedef short bf16x8 __attribute__((ext_vector_type(8)));
typedef float f32x4 __attribute__((ext_vector_type(4)));

// ---------------- helpers ----------------
__device__ __forceinline__ float sp_act(float x) {           // jax.nn.softplus
    return fmaxf(x, 0.0f) + log1pf(expf(-fabsf(x)));
}
__device__ __forceinline__ float lap_cdf(float x, float beta) {
    return (x <= 0.0f) ? 0.5f * expf(x / beta) : 1.0f - 0.5f * expf(-x / beta);
}
__device__ __forceinline__ float sigm(float x) { return 1.0f / (1.0f + expf(-x)); }

__device__ __forceinline__ ushort_t f2bf(float x) {   // RNE float->bf16
    union { float f; unsigned int u; } c; c.f = x;
    unsigned int u = c.u + 0x7FFF + ((c.u >> 16) & 1);
    return (ushort_t)(u >> 16);
}
__device__ __forceinline__ float bf2f(ushort_t s) {
    union { unsigned int u; float f; } c; c.u = ((unsigned int)s) << 16;
    return c.f;
}
// split x = hi + lo (both bf16; bf16 has fp32 exponent range -> no denorm risk)
__device__ __forceinline__ void split2(float v, ushort_t& hi, ushort_t& lo) {
    hi = f2bf(v);
    lo = f2bf(v - bf2f(hi));
}
// activation LDS pair layout: [k/8][P][ hi:8 | lo:8 ]
template<int P>
__device__ __forceinline__ int aidx(int p, int n) { return ((n >> 3) * P + p) * 16 + (n & 7); }

__device__ __forceinline__ void mfma16x16x32(f32x4& c, bf16x8 a, bf16x8 b) {
    asm("v_mfma_f32_16x16x32_bf16 %0, %1, %2, %0" : "+v"(c) : "v"(a), "v"(b));
}

// ---------------- split-precision MFMA tile GEMM ----------------
// OUT[p][n] = act( sum_k A[p][k]*B[k][n] + bias[n] ), p<P=PM*16, n<256, K=KSTEPS*32
// SPLIT: A pair-layout LDS, B pair-packed global, 3 MFMAs (AhBh+AhBl+AlBh)
// !SPLIT (lite): A hi-only read, B compact-packed, 1 MFMA
// 256 threads; wave w owns cols [64w,64w+64). MODE: 0 linear, 1 softplus, 2 relu
template<int MODE, int KSTEPS, bool BIAS, int PM, bool SPLIT>
__device__ __forceinline__ void mfma_gemm(const ushort_t* __restrict__ A,
                                          const ushort_t* __restrict__ Bp,
                                          const float* __restrict__ bias,
                                          ushort_t* __restrict__ OUT)
{
    constexpr int P = PM * 16;
    const int t = threadIdx.x;
    const int wave = t >> 6, lane = t & 63;
    const int r16 = lane & 15, kg = lane >> 4;
    f32x4 acc[PM][4];
#pragma unroll
    for (int m = 0; m < PM; ++m)
#pragma unroll
        for (int nf = 0; nf < 4; ++nf) acc[m][nf] = 0.0f;

#pragma unroll
    for (int ks = 0; ks < KSTEPS; ++ks) {
        bf16x8 ah[PM], al[PM], bh[4], bl[4];
#pragma unroll
        for (int m = 0; m < PM; ++m) {
            const int ab = ((ks * 4 + kg) * P + m * 16 + r16) * 16;
            ah[m] = *(const bf16x8*)(A + ab);
            if (SPLIT) al[m] = *(const bf16x8*)(A + ab + 8);
        }
#pragma unroll
        for (int nf = 0; nf < 4; ++nf) {
            const int n = wave * 64 + nf * 16 + r16;
            if (SPLIT) {
                const int bb = ((ks * 256 + n) * 4 + kg) * 16;
                bh[nf] = *(const bf16x8*)(Bp + bb);
                bl[nf] = *(const bf16x8*)(Bp + bb + 8);
            } else {
                const int bb = ((ks * 256 + n) * 4 + kg) * 8;
                bh[nf] = *(const bf16x8*)(Bp + bb);
            }
        }
#pragma unroll
        for (int m = 0; m < PM; ++m)
#pragma unroll
            for (int nf = 0; nf < 4; ++nf) {
                mfma16x16x32(acc[m][nf], ah[m], bh[nf]);
                if (SPLIT) {
                    mfma16x16x32(acc[m][nf], ah[m], bl[nf]);
                    mfma16x16x32(acc[m][nf], al[m], bh[nf]);
                }
            }
    }
    // epilogue: D row = (lane>>4)*4 + reg, col = lane&15  [HW-verified]
#pragma unroll
    for (int nf = 0; nf < 4; ++nf) {
        const int n = wave * 64 + nf * 16 + r16;
        float bv = 0.0f;
        if (BIAS) bv = bias[n];
#pragma unroll
        for (int m = 0; m < PM; ++m) {
#pragma unroll
            for (int r = 0; r < 4; ++r) {
                const int p = m * 16 + kg * 4 + r;
                float v = acc[m][nf][r] + bv;
                if (MODE == 1) v = sp_act(v);
                if (MODE == 2) v = fmaxf(v, 0.0f);
                ushort_t hi, lo;
                split2(v, hi, lo);
                const int ob = aidx<P>(p, n);
                OUT[ob] = hi; OUT[ob + 8] = lo;
            }
        }
    }
}

// ---------------- prep: pack weights (split pairs / lite compact) ----------------
__global__ __launch_bounds__(256) void prep_kernel(
    const float* __restrict__ w1, const float* __restrict__ w2, const float* __restrict__ w3,
    const float* __restrict__ rw0, const float* __restrict__ rw1,
    ushort_t* __restrict__ pw1T, ushort_t* __restrict__ pw2T, ushort_t* __restrict__ pw3T,
    ushort_t* __restrict__ pw2B, ushort_t* __restrict__ pw1B,
    ushort_t* __restrict__ pwR1, ushort_t* __restrict__ pwR0,
    float* __restrict__ w3c0)
{
    const int k = blockIdx.x, mat = blockIdx.y, n = threadIdx.x;
    const int K = (mat == 6) ? 288 : 256;
    if (k >= K) return;
    float v = 0.0f; ushort_t* dst = pw1T; bool lite = false;
    switch (mat) {
        case 0: v = w1[k * 256 + n]; dst = pw1T; break;
        case 1: v = w2[k * 256 + n]; dst = pw2T; break;
        case 2: v = w3[k * 257 + 1 + n]; dst = pw3T;
                if (n == 0) w3c0[k] = w3[k * 257];
                break;
        case 3: v = w2[n * 256 + k]; dst = pw2B; lite = true; break;  // B = w2^T
        case 4: v = w1[n * 256 + k]; dst = pw1B; lite = true; break;  // B = w1^T
        case 5: v = rw1[k * 256 + n]; dst = pwR1; break;
        case 6: v = (k < 256) ? rw0[(9 + k) * 256 + n]
                  : (k < 265 ? rw0[(k - 256) * 256 + n] : 0.0f);
                dst = pwR0; break;
    }
    if (lite) {
        dst[(((k >> 5) * 256 + n) * 4 + ((k >> 3) & 3)) * 8 + (k & 7)] = f2bf(v);
    } else {
        const int b = (((k >> 5) * 256 + n) * 4 + ((k >> 3) & 3)) * 16 + (k & 7);
        ushort_t hi, lo; split2(v, hi, lo);
        dst[b] = hi; dst[b + 8] = lo;
    }
}

// ---------------- coarse SDF (split MFMA, P=64) ----------------
__global__ __launch_bounds__(256, 1) void coarse_kernel(
    const float* __restrict__ rays_o, const float* __restrict__ rays_d,
    const float* __restrict__ w0, const float* __restrict__ b0,
    const float* __restrict__ b1, const float* __restrict__ b2,
    const ushort_t* __restrict__ pw1T, const ushort_t* __restrict__ pw2T,
    const float* __restrict__ w3c0, const float* __restrict__ b3,
    float* __restrict__ sdf_out)
{
    __shared__ ushort_t bufA[32768], bufB[32768];   // 64KB each (pair layout, P=64)
    __shared__ float geo[64][3];
    __shared__ float red[256];
    const int t = threadIdx.x;
    const int base = blockIdx.x * 64;

    if (t < 64) {
        const int p = t, pg = base + p;
        const int ray = pg >> 7, i = pg & 127;
        float ox = rays_o[ray*3+0], oy = rays_o[ray*3+1], oz = rays_o[ray*3+2];
        float dx = rays_d[ray*3+0], dy = rays_d[ray*3+1], dz = rays_d[ray*3+2];
        float nm = sqrtf(dx*dx + dy*dy + dz*dz);
        dx /= nm; dy /= nm; dz /= nm;
        float dv = 6.0f * ((float)i / 127.0f);
        geo[p][0] = ox + dx * dv; geo[p][1] = oy + dy * dv; geo[p][2] = oz + dz * dv;
    }
    __syncthreads();
    {   // L0 (fp32) -> bufA
        const int n = t;
        float wa = w0[n], wb = w0[256 + n], wc = w0[512 + n], bb = b0[n];
        for (int p = 0; p < 64; ++p) {
            float z = fmaf(geo[p][0], wa, fmaf(geo[p][1], wb, fmaf(geo[p][2], wc, bb)));
            ushort_t hi, lo; split2(sp_act(z), hi, lo);
            const int ob = aidx<64>(p, n);
            bufA[ob] = hi; bufA[ob + 8] = lo;
        }
    }
    __syncthreads();
    mfma_gemm<1, 8, true, 4, true>(bufA, pw1T, b1, bufB); __syncthreads();
    mfma_gemm<1, 8, true, 4, true>(bufB, pw2T, b2, bufA); __syncthreads();
    {   // sdf head partials: thread = (p, nb), nb in [0,4), 64 cols each
        const int p = t >> 2, nb = t & 3;
        float s = 0.0f;
        for (int k = nb * 64; k < nb * 64 + 64; ++k) {
            const int ob = aidx<64>(p, k);
            s = fmaf(bf2f(bufA[ob]) + bf2f(bufA[ob + 8]), w3c0[k], s);
        }
        red[t] = s;
    }
    __syncthreads();
    if (t < 64) {
        float s = b3[0] + red[t*4] + red[t*4+1] + red[t*4+2] + red[t*4+3];
        sdf_out[base + t] = s;
    }
}

// ---------------- per-ray sampling (fp32, verified in R1) ----------------
__global__ __launch_bounds__(256) void sample_kernel(
    const float* __restrict__ sdf_c,
    const float* __restrict__ alpha_p, const float* __restrict__ beta_p,
    float* __restrict__ d_all_g)
{
    __shared__ float sig[4][128];
    __shared__ float dc[4][128];
    __shared__ float wbuf[4][127];
    __shared__ float cdf[4][128];
    __shared__ float dfine[4][64];
    __shared__ float dall[4][192];
    const int t = threadIdx.x;
    const int wv = t >> 6, lane = t & 63;
    const int ray = blockIdx.x * 4 + wv;
    const float alpha = alpha_p[0], beta = beta_p[0];

    for (int i = lane; i < 128; i += 64) {
        float s = sdf_c[ray * 128 + i];
        sig[wv][i] = alpha * lap_cdf(-s, beta);
        dc[wv][i] = 6.0f * ((float)i / 127.0f);
    }
    __syncthreads();
    if (lane == 0) {
        float T = 1.0f, S = 0.0f;
        for (int i = 0; i < 127; ++i) {
            float delta = dc[wv][i + 1] - dc[wv][i];
            float a = 1.0f - expf(-sig[wv][i] * delta);
            float w = a * T;
            T *= (1.0f - a + 1e-10f);
            wbuf[wv][i] = w;
            S += (w + 1e-5f);
        }
        float c = 0.0f;
        cdf[wv][0] = 0.0f;
        for (int i = 0; i < 127; ++i) {
            c += (wbuf[wv][i] + 1e-5f) / S;
            cdf[wv][i + 1] = c;
        }
    }
    __syncthreads();
    {   // inverse-CDF sample: u = lane/63, searchsorted(cdf, u, side='left')
        float u = (float)lane / 63.0f;
        int lo = 0, hi = 128;
        while (lo < hi) { int m = (lo + hi) >> 1; if (cdf[wv][m] < u) lo = m + 1; else hi = m; }
        int below = lo - 1; if (below < 0) below = 0; if (below > 127) below = 127;
        int above = lo; if (above > 127) above = 127;
        float cb = cdf[wv][below], ca = cdf[wv][above];
        float bb = dc[wv][below], ba = dc[wv][above];
        float den = ca - cb; if (den < 1e-5f) den = 1.0f;
        float tt = (u - cb) / den;
        dfine[wv][lane] = bb + tt * (ba - bb);
    }
    __syncthreads();
    {   // merge (ties: coarse-first)
        float v = dfine[wv][lane];
        int lo = 0, hi = 128;                 // count of coarse <= v
        while (lo < hi) { int m = (lo + hi) >> 1; if (dc[wv][m] <= v) lo = m + 1; else hi = m; }
        dall[wv][lane + lo] = v;
    }
    for (int i = lane; i < 128; i += 64) {
        float v = dc[wv][i];
        int lo = 0, hi = 64;                  // count of fine < v
        while (lo < hi) { int m = (lo + hi) >> 1; if (dfine[wv][m] < v) lo = m + 1; else hi = m; }
        dall[wv][i + lo] = v;
    }
    __syncthreads();
    for (int i = lane; i < 192; i += 64) d_all_g[ray * 192 + i] = dall[wv][i];
}

// ---------------- fine pass (split MFMA, P=32) ----------------
__global__ __launch_bounds__(256, 1) void fine_kernel(
    const float* __restrict__ rays_o, const float* __restrict__ rays_d,
    const float* __restrict__ dall_g,
    const float* __restrict__ w0, const float* __restrict__ b0,
    const float* __restrict__ b1, const float* __restrict__ b2, const float* __restrict__ b3,
    const ushort_t* __restrict__ pw1T, const ushort_t* __restrict__ pw2T,
    const ushort_t* __restrict__ pw3T, const ushort_t* __restrict__ pw2B,
    const ushort_t* __restrict__ pw1B,
    const ushort_t* __restrict__ pwR0, const ushort_t* __restrict__ pwR1,
    const float* __restrict__ w3c0,
    const float* __restrict__ rb0, const float* __restrict__ rb1,
    const float* __restrict__ rw2, const float* __restrict__ rb2,
    float* __restrict__ fsdf, float* __restrict__ frgb)
{
    __shared__ ushort_t buf0[16384], buf1[16384], buf2[16384];  // 32KB each (P=32 pairs)
    __shared__ ushort_t fbuf[18432];                            // 36KB, K=288
    __shared__ float geo[32][6];
    __shared__ float red[768];
    const int t = threadIdx.x;
    const int base = blockIdx.x * 32;

    if (t < 32) {
        const int p = t, pg = base + p;
        const int ray = pg / 192, i = pg - ray * 192;
        float ox = rays_o[ray*3+0], oy = rays_o[ray*3+1], oz = rays_o[ray*3+2];
        float dx = rays_d[ray*3+0], dy = rays_d[ray*3+1], dz = rays_d[ray*3+2];
        float nm = sqrtf(dx*dx + dy*dy + dz*dz);
        dx /= nm; dy /= nm; dz /= nm;
        float dv = dall_g[ray * 192 + i];
        float px = ox + dx * dv, py = oy + dy * dv, pz = oz + dz * dv;
        geo[p][0] = px; geo[p][1] = py; geo[p][2] = pz;
        geo[p][3] = dx; geo[p][4] = dy; geo[p][5] = dz;
        // radiance K-order: feat 0..255, pts 256..258, vdirs 259..261, normals 262..264
        ushort_t hi, lo; int ob;
        split2(px, hi, lo); ob = aidx<32>(p, 256); fbuf[ob] = hi; fbuf[ob+8] = lo;
        split2(py, hi, lo); ob = aidx<32>(p, 257); fbuf[ob] = hi; fbuf[ob+8] = lo;
        split2(pz, hi, lo); ob = aidx<32>(p, 258); fbuf[ob] = hi; fbuf[ob+8] = lo;
        split2(dx, hi, lo); ob = aidx<32>(p, 259); fbuf[ob] = hi; fbuf[ob+8] = lo;
        split2(dy, hi, lo); ob = aidx<32>(p, 260); fbuf[ob] = hi; fbuf[ob+8] = lo;
        split2(dz, hi, lo); ob = aidx<32>(p, 261); fbuf[ob] = hi; fbuf[ob+8] = lo;
    }
    for (int idx = t; idx < 32 * 23; idx += 256) {   // zero pad k=265..287
        int p = idx & 31, k = 265 + (idx >> 5);
        const int ob = aidx<32>(p, k);
        fbuf[ob] = 0; fbuf[ob + 8] = 0;
    }
    __syncthreads();
    {   // SDF L0 (fp32) -> buf0 = h0
        const int n = t;
        float wa = w0[n], wb = w0[256 + n], wc = w0[512 + n], bb = b0[n];
        for (int p = 0; p < 32; ++p) {
            float z = fmaf(geo[p][0], wa, fmaf(geo[p][1], wb, fmaf(geo[p][2], wc, bb)));
            ushort_t hi, lo; split2(sp_act(z), hi, lo);
            const int ob = aidx<32>(p, n);
            buf0[ob] = hi; buf0[ob + 8] = lo;
        }
    }
    __syncthreads();
    mfma_gemm<1, 8, true, 2, true>(buf0, pw1T, b1, buf1); __syncthreads();    // h1
    mfma_gemm<1, 8, true, 2, true>(buf1, pw2T, b2, buf2); __syncthreads();    // h2
    mfma_gemm<0, 8, true, 2, true>(buf2, pw3T, b3 + 1, fbuf); __syncthreads();// feat
    {   // sdf head partials (p, nb) + g2' -> buf0
        const int p = t >> 3, nb = t & 7;
        float s = 0.0f;
        for (int k = nb * 32; k < nb * 32 + 32; ++k) {
            const int ob = aidx<32>(p, k);
            s = fmaf(bf2f(buf2[ob]) + bf2f(buf2[ob + 8]), w3c0[k], s);
        }
        red[t] = s;
        // g2' = (1 - exp(-h2)) * w3c0[n], col n = t
        const int n = t;
        const float wc0 = w3c0[n];
        for (int p2 = 0; p2 < 32; ++p2) {
            const int ob = aidx<32>(p2, n);
            float h = bf2f(buf2[ob]) + bf2f(buf2[ob + 8]);
            ushort_t hi, lo; split2((1.0f - expf(-h)) * wc0, hi, lo);
            buf0[ob] = hi; buf0[ob + 8] = lo;
        }
    }
    __syncthreads();
    if (t < 32) {
        float s = b3[0];
#pragma unroll
        for (int nb = 0; nb < 8; ++nb) s += red[t * 8 + nb];
        fsdf[base + t] = s;
    }
    __syncthreads();
    mfma_gemm<0, 8, false, 2, false>(buf0, pw2B, nullptr, buf2); __syncthreads();  // g1 (lite)
    {   // g1' = g1 * (1 - exp(-h1))
        const int n = t;
        for (int p = 0; p < 32; ++p) {
            const int ob = aidx<32>(p, n);
            float g = bf2f(buf2[ob]) + bf2f(buf2[ob + 8]);
            float h = bf2f(buf1[ob]) + bf2f(buf1[ob + 8]);
            ushort_t hi, lo; split2(g * (1.0f - expf(-h)), hi, lo);
            buf2[ob] = hi; buf2[ob + 8] = lo;
        }
    }
    __syncthreads();
    mfma_gemm<0, 8, false, 2, false>(buf2, pw1B, nullptr, buf0); __syncthreads();  // g0 (lite)
    {   // normals partials: thread = (p, nb), 32 cols each
        const int p = t >> 3, nb = t & 7;
        float px = geo[p][0], py = geo[p][1], pz = geo[p][2];
        float pa = 0.f, pb = 0.f, pc = 0.f;
        for (int k = nb * 32; k < nb * 32 + 32; ++k) {
            float wa = w0[k], wb = w0[256+k], wc = w0[512+k];
            float z = fmaf(px, wa, fmaf(py, wb, fmaf(pz, wc, b0[k])));
            float g = bf2f(buf0[aidx<32>(p, k)]) * sigm(z);
            pa = fmaf(wa, g, pa); pb = fmaf(wb, g, pb); pc = fmaf(wc, g, pc);
        }
        red[t * 3 + 0] = pa; red[t * 3 + 1] = pb; red[t * 3 + 2] = pc;
    }
    __syncthreads();
    if (t < 32) {
        const int p = t;
        float nx = 0.f, ny = 0.f, nz = 0.f;
#pragma unroll
        for (int nb = 0; nb < 8; ++nb) {
            nx += red[(p * 8 + nb) * 3 + 0];
            ny += red[(p * 8 + nb) * 3 + 1];
            nz += red[(p * 8 + nb) * 3 + 2];
        }
        float inv = 1.0f / (sqrtf(nx*nx + ny*ny + nz*nz) + 1e-7f);
        ushort_t hi, lo; int ob;
        split2(nx * inv, hi, lo); ob = aidx<32>(p, 262); fbuf[ob] = hi; fbuf[ob+8] = lo;
        split2(ny * inv, hi, lo); ob = aidx<32>(p, 263); fbuf[ob] = hi; fbuf[ob+8] = lo;
        split2(nz * inv, hi, lo); ob = aidx<32>(p, 264); fbuf[ob] = hi; fbuf[ob+8] = lo;
    }
    __syncthreads();
    mfma_gemm<2, 9, true, 2, true>(fbuf, pwR0, rb0, buf1); __syncthreads();   // rad h1 (K=288)
    mfma_gemm<2, 8, true, 2, true>(buf1, pwR1, rb1, buf2); __syncthreads();   // rad h2
    {   // rgb head partials
        const int p = t >> 3, nb = t & 7;
        float s0 = 0.f, s1 = 0.f, s2 = 0.f;
        for (int k = nb * 32; k < nb * 32 + 32; ++k) {
            const int ob = aidx<32>(p, k);
            float f = bf2f(buf2[ob]) + bf2f(buf2[ob + 8]);
            s0 = fmaf(f, rw2[k*3+0], s0);
            s1 = fmaf(f, rw2[k*3+1], s1);
            s2 = fmaf(f, rw2[k*3+2], s2);
        }
        red[t * 3 + 0] = s0; red[t * 3 + 1] = s1; red[t * 3 + 2] = s2;
    }
    __syncthreads();
    if (t < 32) {
        const int p = t;
        float s0 = rb2[0], s1 = rb2[1], s2 = rb2[2];
#pragma unroll
        for (int nb = 0; nb < 8; ++nb) {
            s0 += red[(p * 8 + nb) * 3 + 0];
            s1 += red[(p * 8 + nb) * 3 + 1];
            s2 += red[(p * 8 + nb) * 3 + 2];
        }
        frgb[(base + p) * 3 + 0] = sigm(s0);
        frgb[(base + p) * 3 + 1] = sigm(s1);
        frgb[(base + p) * 3 + 2] = sigm(s2);
    }
}

// ---------------- composite (fp32, verified in R1) ----------------
__global__ __launch_bounds__(256) void composite_kernel(
    const float* __restrict__ dall_g, const float* __restrict__ fsdf,
    const float* __restrict__ frgb,
    const float* __restrict__ alpha_p, const float* __restrict__ beta_p,
    float* __restrict__ out)
{
    __shared__ float aa[4][192];
    __shared__ float da[4][192];
    const int t = threadIdx.x;
    const int wv = t >> 6, lane = t & 63;
    const int ray = blockIdx.x * 4 + wv;
    const float alpha = alpha_p[0], beta = beta_p[0];

    for (int i = lane; i < 192; i += 64) da[wv][i] = dall_g[ray * 192 + i];
    __syncthreads();
    for (int i = lane; i < 192; i += 64) {
        float s = fsdf[ray * 192 + i];
        float sg = alpha * lap_cdf(-s, beta);
        float delta = (i < 191) ? (da[wv][i + 1] - da[wv][i]) : 1e10f;
        aa[wv][i] = 1.0f - expf(-sg * delta);
    }
    __syncthreads();
    if (lane == 0) {
        float T = 1.0f, r0 = 0.f, r1 = 0.f, r2 = 0.f;
        for (int i = 0; i < 192; ++i) {
            float a = aa[wv][i];
            float w = a * T;
            T *= (1.0f - a + 1e-10f);
            const float* rp = frgb + (ray * 192 + i) * 3;
            r0 = fmaf(w, rp[0], r0);
            r1 = fmaf(w, rp[1], r1);
            r2 = fmaf(w, rp[2], r2);
        }
        out[ray * 3 + 0] = r0; out[ray * 3 + 1] = r1; out[ray * 3 + 2] = r2;
    }
}

// ---------------- launch ----------------
extern "C" void kernel_launch(void* const* d_in, const int* in_sizes, int n_in,
                              void* d_out, int out_size, void* d_ws, size_t ws_size,
                              hipStream_t stream) {
    const float* rays_o = (const float*)d_in[0];
    const float* rays_d = (const float*)d_in[1];
    const float* alpha  = (const float*)d_in[2];
    const float* beta   = (const float*)d_in[3];
    const float* sw0 = (const float*)d_in[4];
    const float* sb0 = (const float*)d_in[5];
    const float* sw1 = (const float*)d_in[6];
    const float* sb1 = (const float*)d_in[7];
    const float* sw2 = (const float*)d_in[8];
    const float* sb2 = (const float*)d_in[9];
    const float* sw3 = (const float*)d_in[10];
    const float* sb3 = (const float*)d_in[11];
    const float* rw0 = (const float*)d_in[12];
    const float* rb0 = (const float*)d_in[13];
    const float* rw1 = (const float*)d_in[14];
    const float* rb1 = (const float*)d_in[15];
    const float* rw2 = (const float*)d_in[16];
    const float* rb2 = (const float*)d_in[17];

    // workspace layout (ushort counts)
    ushort_t* wsu = (ushort_t*)d_ws;
    ushort_t* pw1T = wsu;              // split: 131072 each
    ushort_t* pw2T = pw1T + 131072;
    ushort_t* pw3T = pw2T + 131072;
    ushort_t* pwR1 = pw3T + 131072;
    ushort_t* pwR0 = pwR1 + 131072;    // split K=288: 147456
    ushort_t* pw2B = pwR0 + 147456;    // lite: 65536 each
    ushort_t* pw1B = pw2B + 65536;
    float* wsf = (float*)(pw1B + 65536);
    float* w3c0  = wsf;               wsf += 256;
    float* sdf_c = wsf;               wsf += RAYS * 128;
    float* dall  = wsf;               wsf += RAYS * 192;
    float* fsdf  = wsf;               wsf += RAYS * 192;
    float* frgb  = wsf;               wsf += RAYS * 192 * 3;

    prep_kernel<<<dim3(288, 7), 256, 0, stream>>>(
        sw1, sw2, sw3, rw0, rw1, pw1T, pw2T, pw3T, pw2B, pw1B, pwR1, pwR0, w3c0);
    coarse_kernel<<<RAYS * 128 / 64, 256, 0, stream>>>(
        rays_o, rays_d, sw0, sb0, sb1, sb2, pw1T, pw2T, w3c0, sb3, sdf_c);
    sample_kernel<<<RAYS / 4, 256, 0, stream>>>(sdf_c, alpha, beta, dall);
    fine_kernel<<<RAYS * 192 / 32, 256, 0, stream>>>(
        rays_o, rays_d, dall,
        sw0, sb0, sb1, sb2, sb3,
        pw1T, pw2T, pw3T, pw2B, pw1B, pwR0, pwR1,
        w3c0, rb0, rb1, rw2, rb2,
        fsdf, frgb);
    composite_kernel<<<RAYS / 4, 256, 0, stream>>>(dall, fsdf, frgb, alpha, beta, (float*)d_out);
}